// Round 11
// baseline (54.258 us; speedup 1.0000x reference)
//
#include <hip/hip_runtime.h>
#include <hip/hip_bf16.h>

// Hopf oscillator scan: B=32, T=1000, D=512.
// Producer/consumer wave specialization, 256 blocks x 128 threads (2 waves).
//   wave 0 (consumer): reg-burst IN reads, 20-step recurrence with
//     INCREMENTAL ROTATION instead of sin/cos: (c,s) *= (cosD, sinD),
//     cosD~1-q/2+q^2/24, sinD~D(1-q/6), q=D^2, |D|<=~0.09 rad.
//     R9 post-mortem: consumer is issue-bound and 2 trans/step (~32cy wave64)
//     were 57% of it. Error <=D^5/120/step -> <5e-5 over 1000 steps; per-body
//     first-order renorm kills amplitude drift. No trans ops remain.
//   wave 1 (producer): global_load_lds dwordx4 into 4-deep IN ring (3 bodies
//     ahead), drains OUT (sealed at previous barrier) BEFORE the vmcnt wait
//     so the drain overlaps load pacing instead of following it.
// Raw s_barrier per body; hand-counted vmcnt(N), FIFO-simulated:
//   after(n) = 10*[(n>=1)+(n>=2)+(n>=3)+(n+2<NB)+(n+3<NB)]  (max 50 < 63).

#define B 32
#define T 1000
#define D 512
#define DTc 0.001f
#define K_IN 0.005f               // INPUT_SCALER * DT
#define TWO_PI 6.283185307179586f
#define U 20                      // steps per body
#define NB (T / U)                // 50 bodies
#define NOPS (U / 4)              // 5 glds/drain ops per array per body
#define RING 4                    // IN ring depth

typedef float v4f __attribute__((ext_vector_type(4)));
typedef const __attribute__((address_space(1))) float gfloat;
typedef __attribute__((address_space(3))) float lfloat;

#define SCHEDB() __builtin_amdgcn_sched_barrier(0)
#define BAR()    __builtin_amdgcn_s_barrier()
// s_waitcnt simm16 (gfx9): [3:0]=vmcnt lo, [15:14]=vmcnt hi, [6:4]=expcnt, [11:8]=lgkmcnt
#define W_LGKM0  0xC07F   // lgkmcnt(0) only
#define W_VM20   0x4F74   // vmcnt(20) only
#define W_VM30   0x4F7E   // vmcnt(30) only
#define W_VM40   0x8F78   // vmcnt(40) only
#define W_VM50   0xCF72   // vmcnt(50) only

__global__ __launch_bounds__(128, 1) void hopf_scan(
    const float* __restrict__ Xr, const float* __restrict__ Xi,
    const float* __restrict__ om,
    float* __restrict__ zr, float* __restrict__ zi) {
    const int tid = threadIdx.x;
    const int bb = blockIdx.x;            // 0..255
    const int b = bb >> 3;
    const int dblk = (bb & 7) << 6;       // 64-d block
    const size_t blkoff = (size_t)b * (T * D) + dblk;

    __shared__ __align__(16) float INr[RING][U][64];   // 4-deep input ring
    __shared__ __align__(16) float INi[RING][U][64];
    __shared__ __align__(16) float OUTr[2][U][64];     // double-buffered out
    __shared__ __align__(16) float OUTi[2][U][64];

    if (tid < 64) {
        // ---------------- consumer wave: LDS + VALU only ----------------
        const int i = tid;
        // rad/step: omega*dt = (om*10 + 0.1) * 2pi * dt
        const float od = __builtin_fmaf(om[dblk + i], 10.0f, 0.1f) * (TWO_PI * DTc);
        float r = 1.0f, c = 1.0f, s = 0.0f;   // cos/sin of running phase

        BAR();                            // body 0 staged by producer
        for (int n = 0; n < NB; ++n) {
            const int ib = n & 3, ob = n & 1;

            float xr[U], xi[U];
#pragma unroll
            for (int t = 0; t < U; ++t) {   // reg-burst: latency pipelines
                xr[t] = INr[ib][t][i];
                xi[t] = INi[ib][t][i];
            }
            SCHEDB();

#pragma unroll
            for (int t = 0; t < U; ++t) {
                // D = omega*dt - K*xi*sin(phi_old)   (radians, |D| <= ~0.09)
                const float m   = K_IN * xi[t];
                const float dlt = __builtin_fmaf(-m, s, od);
                const float q   = dlt * dlt;
                const float pc  = __builtin_fmaf(q, __builtin_fmaf(q, 4.16666667e-2f, -0.5f), 1.0f);
                const float ps  = dlt * __builtin_fmaf(q, -1.66666667e-1f, 1.0f);
                // r update uses OLD c (cos phi_old)
                const float omr2 = __builtin_fmaf(-r, r, 1.0f);
                r = __builtin_fmaf(omr2 * r, DTc, r);
                r = __builtin_fmaf(K_IN * xr[t], c, r);
                // rotate (c,s) by D
                const float cn = __builtin_fmaf(-s, ps, c * pc);
                const float sn = __builtin_fmaf(c, ps, s * pc);
                c = cn; s = sn;
                OUTr[ob][t][i] = r * c;
                OUTi[ob][t][i] = r * s;
            }
            // first-order renorm of (c,s): h = 1.5 - 0.5*(c^2+s^2)
            {
                const float n2 = __builtin_fmaf(c, c, s * s);
                const float h = __builtin_fmaf(-0.5f, n2, 1.5f);
                c *= h; s *= h;
            }
            __builtin_amdgcn_s_waitcnt(W_LGKM0);  // seal OUT writes
            SCHEDB();
            BAR();
        }
    } else {
        // ---------------- producer wave: all global traffic ----------------
        const int i = tid - 64;           // lane within wave
        const int ts = i >> 4;            // sub-step 0..3 of a glds op
        const int dq = (i & 15) << 2;     // d quad
        const float* __restrict__ xr_blk = Xr + blkoff;
        const float* __restrict__ xi_blk = Xi + blkoff;
        float* __restrict__ zr_blk = zr + blkoff;
        float* __restrict__ zi_blk = zi + blkoff;

        auto issueglds = [&](int body) {
            const int buf = body & 3;
#pragma unroll
            for (int k = 0; k < NOPS; ++k) {
                const size_t off = (size_t)(body * U + 4 * k + ts) * D + dq;
                __builtin_amdgcn_global_load_lds((gfloat*)(xr_blk + off),
                                                 (lfloat*)&INr[buf][4 * k][0], 16, 0, 0);
                __builtin_amdgcn_global_load_lds((gfloat*)(xi_blk + off),
                                                 (lfloat*)&INi[buf][4 * k][0], 16, 0, 0);
            }
        };
        auto drainbody = [&](int body) {
            const int ob = body & 1;
#pragma unroll
            for (int k = 0; k < NOPS; ++k) {
                const size_t off = (size_t)(body * U + 4 * k + ts) * D + dq;
                const v4f vr = *reinterpret_cast<const v4f*>(&OUTr[ob][4 * k + ts][dq]);
                const v4f vi = *reinterpret_cast<const v4f*>(&OUTi[ob][4 * k + ts][dq]);
                __builtin_nontemporal_store(vr, reinterpret_cast<v4f*>(zr_blk + off));
                __builtin_nontemporal_store(vi, reinterpret_cast<v4f*>(zi_blk + off));
            }
        };

        // prologue: bodies 0,1,2 in flight; body 0 landed when <=20 newer remain
        issueglds(0);
        issueglds(1);
        issueglds(2);
        __builtin_amdgcn_s_waitcnt(W_VM20);
        SCHEDB();
        BAR();

        for (int n = 0; n < NB; ++n) {
            if (n + 3 < NB) issueglds(n + 3);
            SCHEDB();
            if (n >= 1) drainbody(n - 1);   // sealed at barrier n-1; overlaps wait
            SCHEDB();
            if (n + 1 < NB) {
                // wait until body n+1's loads retired (FIFO-counted newer ops,
                // incl. drain stores issued this and prior rounds)
                const int after = 10 * ((n >= 1) + (n >= 2) + (n >= 3) +
                                        (n + 2 < NB) + (n + 3 < NB));
                if (after >= 50)      __builtin_amdgcn_s_waitcnt(W_VM50);
                else if (after == 40) __builtin_amdgcn_s_waitcnt(W_VM40);
                else if (after == 30) __builtin_amdgcn_s_waitcnt(W_VM30);
                else                  __builtin_amdgcn_s_waitcnt(W_VM20);
            }
            SCHEDB();
            BAR();
        }
        drainbody(NB - 1);                  // sealed at final barrier
    }
}

extern "C" void kernel_launch(void* const* d_in, const int* in_sizes, int n_in,
                              void* d_out, int out_size, void* d_ws, size_t ws_size,
                              hipStream_t stream) {
    const float* Xr = (const float*)d_in[0];
    const float* Xi = (const float*)d_in[1];
    const float* om = (const float*)d_in[2];
    float* zr = (float*)d_out;
    float* zi = zr + (size_t)B * T * D;   // tuple output 2, flat-concatenated

    hopf_scan<<<dim3(B * D / 64), dim3(128), 0, stream>>>(Xr, Xi, om, zr, zi);
}

// Round 12
// 45.085 us; speedup vs baseline: 1.2035x; 1.2035x over previous
//
#include <hip/hip_runtime.h>
#include <hip/hip_bf16.h>

// Hopf oscillator scan: B=32, T=1000, D=512.
// THREE-wave specialization, 256 blocks x 192 threads:
//   wave 0 (consumer): identical to R7 best — reg-burst IN reads, 20-step
//     recurrence (phi in revolutions, raw v_sin/v_cos), OUT write burst,
//     lgkm seal. (R10 post-mortem: rotation-instead-of-sin REFUTED; trans
//     ops are cheap, round time tracks consumer length 1:1.)
//   wave 1 (loader): global_load_lds dwordx4 only, 4-deep IN ring, 3 bodies
//     ahead. Its vmcnt queue holds ONLY loads now -> steady wait vmcnt(20).
//   wave 2 (drainer): OUT[n-1] -> global (b128 LDS reads + nt x4 stores),
//     entirely off the round-critical path (has the whole round of slack).
// R7's producer serialized issue+wait+drain between barriers (~1100cy tail on
// top of the ~1000cy consumer); splitting removes the drain+store coupling.
// Raw s_barrier per body syncs all 3 waves.

#define B 32
#define T 1000
#define D 512
#define DTc 0.001f
#define K_IN 0.005f               // INPUT_SCALER * DT
#define KREV 7.95774715e-4f       // INPUT_SCALER * DT / (2*pi)
#define U 20                      // steps per body
#define NB (T / U)                // 50 bodies
#define NOPS (U / 4)              // 5 glds/drain ops per array per body
#define RING 4                    // IN ring depth

typedef float v4f __attribute__((ext_vector_type(4)));
typedef const __attribute__((address_space(1))) float gfloat;
typedef __attribute__((address_space(3))) float lfloat;

#define SCHEDB() __builtin_amdgcn_sched_barrier(0)
#define BAR()    __builtin_amdgcn_s_barrier()
// s_waitcnt simm16 (gfx9): [3:0]=vmcnt lo, [15:14]=vmcnt hi, [6:4]=expcnt, [11:8]=lgkmcnt
#define W_LGKM0  0xC07F   // lgkmcnt(0) only
#define W_VM0    0x0F70   // vmcnt(0)  only
#define W_VM10   0x0F7A   // vmcnt(10) only
#define W_VM20   0x4F74   // vmcnt(20) only

__global__ __launch_bounds__(192, 1) void hopf_scan(
    const float* __restrict__ Xr, const float* __restrict__ Xi,
    const float* __restrict__ om,
    float* __restrict__ zr, float* __restrict__ zi) {
    const int tid = threadIdx.x;
    const int bb = blockIdx.x;            // 0..255
    const int b = bb >> 3;
    const int dblk = (bb & 7) << 6;       // 64-d block
    const size_t blkoff = (size_t)b * (T * D) + dblk;

    __shared__ __align__(16) float INr[RING][U][64];   // 4-deep input ring
    __shared__ __align__(16) float INi[RING][U][64];
    __shared__ __align__(16) float OUTr[2][U][64];     // double-buffered out
    __shared__ __align__(16) float OUTi[2][U][64];

    if (tid < 64) {
        // ---------------- wave 0: consumer (LDS + VALU only) ----------------
        const int i = tid;
        // rev/step: f_Hz * dt = (om*10 + 0.1) * dt
        const float od = __builtin_fmaf(om[dblk + i], 10.0f, 0.1f) * DTc;
        float r = 1.0f, phi = 0.0f, c = 1.0f, s = 0.0f;  // phi in revolutions

        BAR();                            // body 0 staged by loader
        for (int n = 0; n < NB; ++n) {
            const int ib = n & 3, ob = n & 1;

            float xr[U], xi[U];
#pragma unroll
            for (int t = 0; t < U; ++t) {   // reg-burst: latency pipelines
                xr[t] = INr[ib][t][i];
                xi[t] = INi[ib][t][i];
            }
            SCHEDB();

            float our[U], oui[U];
#pragma unroll
            for (int t = 0; t < U; ++t) {
                const float omr2 = __builtin_fmaf(-r, r, 1.0f);   // 1 - r^2
                r = __builtin_fmaf(omr2 * r, DTc, r);             // + cubic*dt
                r = __builtin_fmaf(K_IN * xr[t], c, r);           // + K*xr*cos
                phi = __builtin_fmaf(-(KREV * xi[t]), s, phi + od);
                s = __builtin_amdgcn_sinf(phi);   // v_sin: input in revs
                c = __builtin_amdgcn_cosf(phi);
                our[t] = r * c;
                oui[t] = r * s;
            }
            SCHEDB();
#pragma unroll
            for (int t = 0; t < U; ++t) {
                OUTr[ob][t][i] = our[t];
                OUTi[ob][t][i] = oui[t];
            }
            __builtin_amdgcn_s_waitcnt(W_LGKM0);  // OUT complete before BAR
            SCHEDB();
            BAR();
        }
    } else if (tid < 128) {
        // ---------------- wave 1: loader (global->LDS only) -----------------
        const int i = tid - 64;
        const int ts = i >> 4;            // sub-step 0..3 of a glds op
        const int dq = (i & 15) << 2;     // d quad
        const float* __restrict__ xr_blk = Xr + blkoff;
        const float* __restrict__ xi_blk = Xi + blkoff;

        auto issueglds = [&](int body) {
            const int buf = body & 3;
#pragma unroll
            for (int k = 0; k < NOPS; ++k) {
                const size_t off = (size_t)(body * U + 4 * k + ts) * D + dq;
                __builtin_amdgcn_global_load_lds((gfloat*)(xr_blk + off),
                                                 (lfloat*)&INr[buf][4 * k][0], 16, 0, 0);
                __builtin_amdgcn_global_load_lds((gfloat*)(xi_blk + off),
                                                 (lfloat*)&INi[buf][4 * k][0], 16, 0, 0);
            }
        };

        // prologue: bodies 0,1,2 in flight; body 0 landed when <=20 newer remain
        issueglds(0);
        issueglds(1);
        issueglds(2);
        __builtin_amdgcn_s_waitcnt(W_VM20);
        SCHEDB();
        BAR();

        for (int n = 0; n < NB; ++n) {
            if (n + 3 < NB) issueglds(n + 3);
            SCHEDB();
            if (n + 1 < NB) {
                // queue holds ONLY loads: newer than body n+1's are bodies
                // n+2, n+3 (10 each, if issued).
                const int after = 10 * ((n + 2 < NB) + (n + 3 < NB));
                if (after == 20)      __builtin_amdgcn_s_waitcnt(W_VM20);
                else if (after == 10) __builtin_amdgcn_s_waitcnt(W_VM10);
                else                  __builtin_amdgcn_s_waitcnt(W_VM0);
            }
            SCHEDB();
            BAR();
        }
    } else {
        // ---------------- wave 2: drainer (LDS->global only) ----------------
        const int i = tid - 128;
        const int ts = i >> 4;
        const int dq = (i & 15) << 2;
        float* __restrict__ zr_blk = zr + blkoff;
        float* __restrict__ zi_blk = zi + blkoff;

        auto drainbody = [&](int body) {
            const int ob = body & 1;
#pragma unroll
            for (int k = 0; k < NOPS; ++k) {
                const size_t off = (size_t)(body * U + 4 * k + ts) * D + dq;
                const v4f vr = *reinterpret_cast<const v4f*>(&OUTr[ob][4 * k + ts][dq]);
                const v4f vi = *reinterpret_cast<const v4f*>(&OUTi[ob][4 * k + ts][dq]);
                __builtin_nontemporal_store(vr, reinterpret_cast<v4f*>(zr_blk + off));
                __builtin_nontemporal_store(vi, reinterpret_cast<v4f*>(zi_blk + off));
            }
        };

        BAR();                            // match loader/consumer prologue
        for (int n = 0; n < NB; ++n) {
            // OUT[n-1] was sealed at barrier n-1; drain it during round n.
            // ds_reads are consumed (into store data regs) before BAR, so the
            // buffer is safe to overwrite next round; stores fly uncounted.
            if (n >= 1) drainbody(n - 1);
            SCHEDB();
            BAR();
        }
        drainbody(NB - 1);                // sealed at final barrier
    }
}

extern "C" void kernel_launch(void* const* d_in, const int* in_sizes, int n_in,
                              void* d_out, int out_size, void* d_ws, size_t ws_size,
                              hipStream_t stream) {
    const float* Xr = (const float*)d_in[0];
    const float* Xi = (const float*)d_in[1];
    const float* om = (const float*)d_in[2];
    float* zr = (float*)d_out;
    float* zi = zr + (size_t)B * T * D;   // tuple output 2, flat-concatenated

    hopf_scan<<<dim3(B * D / 64), dim3(192), 0, stream>>>(Xr, Xi, om, zr, zi);
}

// Round 16
// 43.987 us; speedup vs baseline: 1.2335x; 1.0250x over previous
//
#include <hip/hip_runtime.h>
#include <hip/hip_bf16.h>

// Hopf oscillator scan: B=32, T=1000, D=512.
// THREE-wave specialization (R11 base, PASSING code path — asm-store
// experiment of R12-R14 abandoned: 3 distinct corruption modes from
// compiler-invisible store hazards; builtin nt stores already cover nt).
// R15 change: U 20 -> 40 (NB 50 -> 25 rounds), IN ring 4 -> 3 deep.
// Rationale: R8-R11 showed round = max(consumer, HBM pace) + ~650cy fixed
// coupling overhead per round, insensitive to depth/stores/waves. Halving
// the round count halves the total overhead: 25 x (max(2060,2950)+650)
// ~ 90k cy ~ 37.5us.
//   wave 0 (consumer): reg-burst IN reads, 40-step recurrence (phi in
//     revolutions, raw v_sin/v_cos), OUT write burst, lgkm seal.
//   wave 1 (loader): global_load_lds dwordx4, 3-deep ring, 2 bodies ahead,
//     hand-counted vmcnt (loads-only queue: steady vmcnt(20)).
//   wave 2 (drainer): OUT[n-1] -> global (b128 LDS reads + builtin nt x4
//     stores), off the critical path.

#define B 32
#define T 1000
#define D 512
#define DTc 0.001f
#define K_IN 0.005f               // INPUT_SCALER * DT
#define KREV 7.95774715e-4f       // INPUT_SCALER * DT / (2*pi)
#define U 40                      // steps per body
#define NB (T / U)                // 25 bodies
#define NOPS (U / 4)              // 10 glds/drain ops per array per body
#define RING 3                    // IN ring depth

typedef float v4f __attribute__((ext_vector_type(4)));
typedef const __attribute__((address_space(1))) float gfloat;
typedef __attribute__((address_space(3))) float lfloat;

#define SCHEDB() __builtin_amdgcn_sched_barrier(0)
#define BAR()    __builtin_amdgcn_s_barrier()
// s_waitcnt simm16 (gfx9): [3:0]=vmcnt lo, [15:14]=vmcnt hi, [6:4]=expcnt, [11:8]=lgkmcnt
#define W_LGKM0  0xC07F   // lgkmcnt(0) only
#define W_VM0    0x0F70   // vmcnt(0)  only
#define W_VM20   0x4F74   // vmcnt(20) only

__global__ __launch_bounds__(192, 1) void hopf_scan(
    const float* __restrict__ Xr, const float* __restrict__ Xi,
    const float* __restrict__ om,
    float* __restrict__ zr, float* __restrict__ zi) {
    const int tid = threadIdx.x;
    const int bb = blockIdx.x;            // 0..255
    const int b = bb >> 3;
    const int dblk = (bb & 7) << 6;       // 64-d block
    const size_t blkoff = (size_t)b * (T * D) + dblk;

    __shared__ __align__(16) float INr[RING][U][64];   // 3-deep input ring
    __shared__ __align__(16) float INi[RING][U][64];
    __shared__ __align__(16) float OUTr[2][U][64];     // double-buffered out
    __shared__ __align__(16) float OUTi[2][U][64];

    if (tid < 64) {
        // ---------------- wave 0: consumer (LDS + VALU only) ----------------
        const int i = tid;
        // rev/step: f_Hz * dt = (om*10 + 0.1) * dt
        const float od = __builtin_fmaf(om[dblk + i], 10.0f, 0.1f) * DTc;
        float r = 1.0f, phi = 0.0f, c = 1.0f, s = 0.0f;  // phi in revolutions

        BAR();                            // body 0 staged by loader
        int ib = 0;                       // ring slot of body n (mod 3)
        for (int n = 0; n < NB; ++n) {
            const int ob = n & 1;

            float xr[U], xi[U];
#pragma unroll
            for (int t = 0; t < U; ++t) {   // reg-burst: latency pipelines
                xr[t] = INr[ib][t][i];
                xi[t] = INi[ib][t][i];
            }
            SCHEDB();

            float our[U], oui[U];
#pragma unroll
            for (int t = 0; t < U; ++t) {
                const float omr2 = __builtin_fmaf(-r, r, 1.0f);   // 1 - r^2
                r = __builtin_fmaf(omr2 * r, DTc, r);             // + cubic*dt
                r = __builtin_fmaf(K_IN * xr[t], c, r);           // + K*xr*cos
                phi = __builtin_fmaf(-(KREV * xi[t]), s, phi + od);
                s = __builtin_amdgcn_sinf(phi);   // v_sin: input in revs
                c = __builtin_amdgcn_cosf(phi);
                our[t] = r * c;
                oui[t] = r * s;
            }
            SCHEDB();
#pragma unroll
            for (int t = 0; t < U; ++t) {
                OUTr[ob][t][i] = our[t];
                OUTi[ob][t][i] = oui[t];
            }
            __builtin_amdgcn_s_waitcnt(W_LGKM0);  // OUT complete before BAR
            SCHEDB();
            BAR();
            ib = (ib == RING - 1) ? 0 : ib + 1;
        }
    } else if (tid < 128) {
        // ---------------- wave 1: loader (global->LDS only) -----------------
        const int i = tid - 64;
        const int ts = i >> 4;            // sub-step 0..3 of a glds op
        const int dq = (i & 15) << 2;     // d quad
        const float* __restrict__ xr_blk = Xr + blkoff;
        const float* __restrict__ xi_blk = Xi + blkoff;

        auto issueglds = [&](int body, int buf) {
#pragma unroll
            for (int k = 0; k < NOPS; ++k) {
                const size_t off = (size_t)(body * U + 4 * k + ts) * D + dq;
                __builtin_amdgcn_global_load_lds((gfloat*)(xr_blk + off),
                                                 (lfloat*)&INr[buf][4 * k][0], 16, 0, 0);
                __builtin_amdgcn_global_load_lds((gfloat*)(xi_blk + off),
                                                 (lfloat*)&INi[buf][4 * k][0], 16, 0, 0);
            }
        };

        // prologue: bodies 0,1 in flight; body 0 landed when <=20 newer remain
        issueglds(0, 0);
        issueglds(1, 1);
        __builtin_amdgcn_s_waitcnt(W_VM20);
        SCHEDB();
        BAR();

        int bufn = 2;                     // ring slot for body n+2 (mod 3)
        for (int n = 0; n < NB; ++n) {
            if (n + 2 < NB) issueglds(n + 2, bufn);
            SCHEDB();
            if (n + 1 < NB) {
                // loads-only queue: ops newer than body n+1's are body n+2's
                // 20 (if issued).
                if (n + 2 < NB) __builtin_amdgcn_s_waitcnt(W_VM20);
                else            __builtin_amdgcn_s_waitcnt(W_VM0);
            }
            SCHEDB();
            BAR();
            bufn = (bufn == RING - 1) ? 0 : bufn + 1;
        }
    } else {
        // ---------------- wave 2: drainer (LDS->global only) ----------------
        const int i = tid - 128;
        const int ts = i >> 4;
        const int dq = (i & 15) << 2;
        float* __restrict__ zr_blk = zr + blkoff;
        float* __restrict__ zi_blk = zi + blkoff;

        auto drainbody = [&](int body) {
            const int ob = body & 1;
#pragma unroll
            for (int k = 0; k < NOPS; ++k) {
                const size_t off = (size_t)(body * U + 4 * k + ts) * D + dq;
                const v4f vr = *reinterpret_cast<const v4f*>(&OUTr[ob][4 * k + ts][dq]);
                const v4f vi = *reinterpret_cast<const v4f*>(&OUTi[ob][4 * k + ts][dq]);
                __builtin_nontemporal_store(vr, reinterpret_cast<v4f*>(zr_blk + off));
                __builtin_nontemporal_store(vi, reinterpret_cast<v4f*>(zi_blk + off));
            }
        };

        BAR();                            // match loader/consumer prologue
        for (int n = 0; n < NB; ++n) {
            // OUT[n-1] was sealed at barrier n-1; drain it during round n.
            // ds_reads are consumed into store-data regs before BAR (compiler
            // tracks these builtin stores), so the buffer is safe next round.
            if (n >= 1) drainbody(n - 1);
            SCHEDB();
            BAR();
        }
        drainbody(NB - 1);                // sealed at final barrier
    }
}

extern "C" void kernel_launch(void* const* d_in, const int* in_sizes, int n_in,
                              void* d_out, int out_size, void* d_ws, size_t ws_size,
                              hipStream_t stream) {
    const float* Xr = (const float*)d_in[0];
    const float* Xi = (const float*)d_in[1];
    const float* om = (const float*)d_in[2];
    float* zr = (float*)d_out;
    float* zi = zr + (size_t)B * T * D;   // tuple output 2, flat-concatenated

    hopf_scan<<<dim3(B * D / 64), dim3(192), 0, stream>>>(Xr, Xi, om, zr, zi);
}